// Round 10
// baseline (2684.005 us; speedup 1.0000x reference)
//
#include <hip/hip_runtime.h>

#define NN 100000
#define IN_CH 128
#define HID 32
#define OUT_CH 64
#define N_LAYERS 16
#define NB1 2048            // k_agg blocks (4 waves each)
#define EPS_MSG 1e-7f
#define EPS_SM 1e-16f
#define EPS_BN 1e-5f

// ---------------- CSR build (known-good deterministic-order version) ----------------

__global__ void k_hist(const int* __restrict__ dst, int* __restrict__ counts, int E) {
    int i = blockIdx.x * 256 + threadIdx.x;
    if (i < E) atomicAdd(&counts[dst[i]], 1);
}

__global__ void k_scan1(const int* __restrict__ counts, int* __restrict__ rowptr,
                        int* __restrict__ bsum, int n) {
    __shared__ int sh[1024];
    int t = threadIdx.x;
    int i = blockIdx.x * 1024 + t;
    int v = (i < n) ? counts[i] : 0;
    sh[t] = v;
    __syncthreads();
    for (int off = 1; off < 1024; off <<= 1) {
        int tmp = (t >= off) ? sh[t - off] : 0;
        __syncthreads();
        sh[t] += tmp;
        __syncthreads();
    }
    if (i < n) rowptr[i] = sh[t] - v;   // exclusive within chunk
    if (t == 1023) bsum[blockIdx.x] = sh[1023];
}

__global__ void k_scan2(int* __restrict__ bsum, int nb) {
    if (threadIdx.x == 0 && blockIdx.x == 0) {
        int acc = 0;
        for (int b = 0; b < nb; b++) { int v = bsum[b]; bsum[b] = acc; acc += v; }
    }
}

__global__ void k_scan3(int* __restrict__ rowptr, int* __restrict__ cursor,
                        const int* __restrict__ bsum, int n, int E) {
    int i = blockIdx.x * 256 + threadIdx.x;
    if (i < n) {
        int r = rowptr[i] + bsum[i >> 10];
        rowptr[i] = r;
        cursor[i] = r;
    }
    if (i == 0) rowptr[n] = E;
}

// split into [lo,hi) ranges so each dispatch is ~64 us -> layer kernels stay
// visible in the top-5 profile (diagnostic; same atomic mechanism as monolithic)
__global__ void k_scatter(const int* __restrict__ src, const int* __restrict__ dst,
                          int* __restrict__ cursor, int* __restrict__ col,
                          int lo, int hi) {
    int i = lo + blockIdx.x * 256 + threadIdx.x;
    if (i < hi) {
        int d = dst[i];
        int p = atomicAdd(&cursor[d], 1);
        col[p] = src[i];
    }
}

// ---------------- input projection: h0 = x @ w0 + b0 ----------------

__global__ __launch_bounds__(256) void k0(const float* __restrict__ x,
                                          const float* __restrict__ w0,
                                          const float* __restrict__ b0,
                                          float* __restrict__ h) {
    __shared__ float ws[IN_CH * HID];   // 16 KB
    __shared__ float xs[8][IN_CH];      // 4 KB
    int tid = threadIdx.x, c = tid & 31, g = tid >> 5;
    for (int k = tid; k < IN_CH * HID; k += 256) ws[k] = w0[k];
    int d = blockIdx.x * 8 + g;
    float4 xv = ((const float4*)(x + (size_t)d * IN_CH))[c];
    ((float4*)xs[g])[c] = xv;
    __syncthreads();
    float acc = b0[c];
#pragma unroll 16
    for (int k = 0; k < IN_CH; k++) acc += xs[g][k] * ws[k * HID + c];
    h[(size_t)d * HID + c] = acc;
}

// ---------------- per-layer: softmax-agg + residual + lin1 + BN partials ----------------
// WAVE-PER-NODE layout. r9 counters proved k_agg is serial-latency-bound
// (VALU -20% with zero time change). This round: the chain's FRONT END -- the
// two dependent scalar loads (rowptr -> col chunk-0) -- is prefetched one node
// ahead into SGPRs (double-buffered sc[16], zero VGPR cost). Chunk-0 gathers
// then issue immediately at loop entry. Same values, same arithmetic order ->
// bitwise-identical output.

__global__ __launch_bounds__(256) void k_agg(const float* __restrict__ h,
                                             const int* __restrict__ rowptr,
                                             const int* __restrict__ col,
                                             const float* __restrict__ w1,
                                             const float* __restrict__ b1,
                                             float* __restrict__ z,
                                             float* __restrict__ zsum,
                                             int layer) {
    __shared__ float red[256];
    int tid = threadIdx.x;
    int c = tid & 31;                                   // channel within half
    int c64 = tid & 63;                                 // owned z column
    int half = (tid >> 5) & 1;                          // even/odd edge slot
    int wslot = __builtin_amdgcn_readfirstlane(tid >> 6);
    int wid = blockIdx.x * 4 + wslot;                   // wave-uniform

    // register-resident W1 column + bias for this lane's output column
    const float* w1l = w1 + layer * (HID * 64);
    float w1col[HID];
#pragma unroll
    for (int k = 0; k < HID; k++) w1col[k] = w1l[k * 64 + c64];
    float b1v = b1[layer * 64 + c64];

    float sz = 0.f, qz = 0.f;

    const int stride = NB1 * 4;
    int pr0 = 0, pr1 = 0;
    int sc[16];                                         // chunk-0 col words (SGPRs)
#pragma unroll
    for (int q = 0; q < 16; q++) sc[q] = 0;
    if (wid < NN) {
        pr0 = rowptr[wid]; pr1 = rowptr[wid + 1];       // uniform -> s_load
        int cr = __builtin_amdgcn_readfirstlane(pr0);
#pragma unroll
        for (int q = 0; q < 16; q++) sc[q] = col[cr + q];   // pad-safe (+32 pad)
    }

    for (int d = wid; d < NN; d += stride) {
        int r0 = __builtin_amdgcn_readfirstlane(pr0);
        int r1 = __builtin_amdgcn_readfirstlane(pr1);
        // issue next node's rowptr + chunk-0 col loads now (scalar pipe);
        // their ~400cy latency hides under this node's gathers/compute
        int nd = d + stride;
        int nsc[16];
#pragma unroll
        for (int q = 0; q < 16; q++) nsc[q] = 0;
        if (nd < NN) {
            pr0 = rowptr[nd]; pr1 = rowptr[nd + 1];
            int cr = __builtin_amdgcn_readfirstlane(pr0);
#pragma unroll
            for (int q = 0; q < 16; q++) nsc[q] = col[cr + q];
        }
        float den = 0.f, num = 0.f;
        int e0 = r0;
        if (r1 - r0 >= 16) {
            // ---- chunk 0 full (unmasked), from prefetched sc ----
            float vv[8];
#pragma unroll
            for (int p = 0; p < 8; p++) {
                int s = half ? sc[2 * p + 1] : sc[2 * p];
                vv[p] = fmaxf(h[(unsigned)((s << 5) + c)], 0.f) + EPS_MSG;
            }
#pragma unroll
            for (int p = 0; p < 8; p++) {
                float ev = __expf(vv[p]);               // bounded: no max-subtraction
                den += ev;
                num += ev * vv[p];
            }
            e0 += 16;
            // ---- remaining full chunks: unmasked, col loaded in-loop ----
            for (; e0 + 16 <= r1; e0 += 16) {
                float vw[8];
#pragma unroll
                for (int p = 0; p < 8; p++) {
                    int sA = col[e0 + 2 * p];           // uniform -> s_load
                    int sB = col[e0 + 2 * p + 1];
                    int s = half ? sB : sA;
                    vw[p] = fmaxf(h[(unsigned)((s << 5) + c)], 0.f) + EPS_MSG;
                }
#pragma unroll
                for (int p = 0; p < 8; p++) {
                    float ev = __expf(vw[p]);
                    den += ev;
                    num += ev * vw[p];
                }
            }
        }
        int rem = r1 - e0;                              // uniform, 0..15
        if (rem > 8) {
            // ---- tail 9..15: masked 8-gather path ----
            float vv[8];
#pragma unroll
            for (int p = 0; p < 8; p++) {
                int sA, sB;
                if (e0 == r0) { sA = sc[2 * p]; sB = sc[2 * p + 1]; }
                else          { sA = col[e0 + 2 * p]; sB = col[e0 + 2 * p + 1]; }
                int s = half ? sB : sA;
                vv[p] = fmaxf(h[(unsigned)((s << 5) + c)], 0.f) + EPS_MSG;
            }
#pragma unroll
            for (int p = 0; p < 8; p++) {
                float ev = __expf(vv[p]);
                bool ok = (2 * p + half) < rem;
                den += ok ? ev : 0.f;
                num += ok ? ev * vv[p] : 0.f;
            }
        } else if (rem > 0) {
            // ---- tail 1..8: masked 4-gather path (omitted terms were +0.0f) ----
            float vv[4];
#pragma unroll
            for (int p = 0; p < 4; p++) {
                int sA, sB;
                if (e0 == r0) { sA = sc[2 * p]; sB = sc[2 * p + 1]; }
                else          { sA = col[e0 + 2 * p]; sB = col[e0 + 2 * p + 1]; }
                int s = half ? sB : sA;
                vv[p] = fmaxf(h[(unsigned)((s << 5) + c)], 0.f) + EPS_MSG;
            }
#pragma unroll
            for (int p = 0; p < 4; p++) {
                float ev = __expf(vv[p]);
                bool ok = (2 * p + half) < rem;
                den += ok ? ev : 0.f;
                num += ok ? ev * vv[p] : 0.f;
            }
        }
        // merge even/odd partials across the two halves (commutative -> both
        // halves end with bitwise-identical totals)
        den += __shfl_xor(den, 32);
        num += __shfl_xor(num, 32);
        float out = num / (den + EPS_SM) + h[(unsigned)((d << 5) + c)];
        // lin1: z[c64] = b1 + sum_k out[k] * w1[k][c64]; out[k] broadcast via readlane
        float zv = b1v;
#pragma unroll
        for (int k = 0; k < HID; k++) {
            float ok_ = __int_as_float(
                __builtin_amdgcn_readlane(__float_as_int(out), k));
            zv += ok_ * w1col[k];
        }
        z[(size_t)d * 64 + c64] = zv;
        sz += zv; qz += zv * zv;
        // rotate prefetched col buffer
#pragma unroll
        for (int q = 0; q < 16; q++) sc[q] = nsc[q];
    }

    // BN partials: block reduce (4 waves, columns match stride 64), 128 atomics/block
    float* acc = zsum + layer * 128;
    red[tid] = sz;
    __syncthreads();
    if (tid < 64) atomicAdd(&acc[tid], red[tid] + red[tid + 64] + red[tid + 128] + red[tid + 192]);
    __syncthreads();
    red[tid] = qz;
    __syncthreads();
    if (tid < 64) atomicAdd(&acc[64 + tid], red[tid] + red[tid + 64] + red[tid + 128] + red[tid + 192]);
}

// ---------------- BN apply + relu + lin2 + relu (round-8 proven version) ----------------
// 32 nodes/block (3125 blocks). w2 staged once per block, then each thread
// holds its w2 column in 64 VGPRs (amortized over 4 nodes); zs read as float4
// BROADCASTS (16 LDS ops/node vs 128 in the old version).

__global__ __launch_bounds__(256) void k_bn2(const float* __restrict__ z,
                                             const float* __restrict__ zsum,
                                             const float* __restrict__ gamma,
                                             const float* __restrict__ beta,
                                             const float* __restrict__ w2,
                                             const float* __restrict__ b2,
                                             float* __restrict__ hout,
                                             int layer) {
    __shared__ float w2s[64 * HID];   // 8 KB, [k][c] layout
    __shared__ float zs[32][64];      // 8 KB
    int tid = threadIdx.x, c = tid & 31, g = tid >> 5;
    for (int k = tid; k < 64 * HID; k += 256) w2s[k] = w2[layer * (64 * HID) + k];

    // BN scale/shift for channels c and c+32 (same expressions as before -> same bits)
    float S0 = zsum[layer * 128 + c];
    float Q0 = zsum[layer * 128 + 64 + c];
    float mean0 = S0 * (1.0f / NN);
    float var0 = Q0 * (1.0f / NN) - mean0 * mean0;
    float sc0 = gamma[layer * 64 + c] * rsqrtf(var0 + EPS_BN);
    float sh0 = beta[layer * 64 + c] - mean0 * sc0;
    float S1 = zsum[layer * 128 + 32 + c];
    float Q1 = zsum[layer * 128 + 96 + c];
    float mean1 = S1 * (1.0f / NN);
    float var1 = Q1 * (1.0f / NN) - mean1 * mean1;
    float sc1 = gamma[layer * 64 + 32 + c] * rsqrtf(var1 + EPS_BN);
    float sh1 = beta[layer * 64 + 32 + c] - mean1 * sc1;

    int dbase = blockIdx.x * 32;
#pragma unroll
    for (int j = 0; j < 4; j++) {
        int gg = g + 8 * j;
        int d = dbase + gg;
        float z0 = z[(size_t)d * 64 + c] * sc0 + sh0;
        float z1 = z[(size_t)d * 64 + 32 + c] * sc1 + sh1;
        zs[gg][c] = fmaxf(z0, 0.f);
        zs[gg][c + 32] = fmaxf(z1, 0.f);
    }
    __syncthreads();

    // w2 column into registers (conflict-free LDS reads, once per 4 nodes)
    float w2col[64];
#pragma unroll
    for (int k = 0; k < 64; k++) w2col[k] = w2s[k * HID + c];
    float b2v = b2[layer * HID + c];

#pragma unroll
    for (int j = 0; j < 4; j++) {
        int gg = g + 8 * j;
        int d = dbase + gg;
        float acc = b2v;
#pragma unroll
        for (int k = 0; k < 64; k += 4) {
            float4 zq = *(const float4*)&zs[gg][k];   // broadcast read
            acc += zq.x * w2col[k];
            acc += zq.y * w2col[k + 1];
            acc += zq.z * w2col[k + 2];
            acc += zq.w * w2col[k + 3];
        }
        hout[(size_t)d * HID + c] = fmaxf(acc, 0.f);
    }
}

// ---------------- output projection: out = h @ w16 + b16 ----------------

__global__ __launch_bounds__(256) void k_final(const float* __restrict__ h,
                                               const float* __restrict__ w16,
                                               const float* __restrict__ b16,
                                               float* __restrict__ out) {
    __shared__ float ws[HID * OUT_CH];   // 8 KB
    __shared__ float hs[8][HID];
    int tid = threadIdx.x, c = tid & 31, g = tid >> 5;
    for (int k = tid; k < HID * OUT_CH; k += 256) ws[k] = w16[k];
    int d = blockIdx.x * 8 + g;
    hs[g][c] = h[(size_t)d * HID + c];
    __syncthreads();
    float o0 = b16[c], o1 = b16[c + 32];
#pragma unroll
    for (int k = 0; k < HID; k++) {
        float hv = hs[g][k];
        o0 += hv * ws[k * OUT_CH + c];
        o1 += hv * ws[k * OUT_CH + c + 32];
    }
    out[(size_t)d * OUT_CH + c] = o0;
    out[(size_t)d * OUT_CH + 32 + c] = o1;
}

// ---------------- host ----------------

extern "C" void kernel_launch(void* const* d_in, const int* in_sizes, int n_in,
                              void* d_out, int out_size, void* d_ws, size_t ws_size,
                              hipStream_t stream) {
    const float* x      = (const float*)d_in[0];
    const int*   ei     = (const int*)d_in[1];
    const float* w0     = (const float*)d_in[2];
    const float* b0     = (const float*)d_in[3];
    const float* lin1_w = (const float*)d_in[4];
    const float* lin1_b = (const float*)d_in[5];
    const float* gamma  = (const float*)d_in[6];
    const float* beta   = (const float*)d_in[7];
    const float* lin2_w = (const float*)d_in[8];
    const float* lin2_b = (const float*)d_in[9];
    const float* w16    = (const float*)d_in[10];
    const float* b16    = (const float*)d_in[11];
    float* out = (float*)d_out;

    const int E = in_sizes[1] / 2;
    const int* src = ei;
    const int* dst = ei + E;

    // workspace carve-up (all 256B-aligned)
    char* p = (char*)d_ws;
    auto alloc = [&](size_t bytes) {
        char* q = p;
        p += (bytes + 255) & ~(size_t)255;
        return q;
    };
    float* hA       = (float*)alloc((size_t)NN * HID * 4);
    float* hB       = (float*)alloc((size_t)NN * HID * 4);
    float* z        = (float*)alloc((size_t)NN * 64 * 4);
    int*   rowptr   = (int*)alloc((size_t)(NN + 1) * 4);
    int*   cursor   = (int*)alloc((size_t)NN * 4);
    int*   counts   = (int*)alloc((size_t)NN * 4);
    int*   col      = (int*)alloc((size_t)(E + 32) * 4);   // +32 pad for chunked reads
    int*   bsum     = (int*)alloc(1024 * 4);
    float* zsum     = (float*)alloc((size_t)N_LAYERS * 128 * 4);
    (void)ws_size; (void)n_in; (void)out_size;

    // --- zero accumulators + CSR build (once per call; reused by all layers) ---
    hipMemsetAsync(counts, 0, (size_t)NN * 4, stream);
    hipMemsetAsync(zsum, 0, (size_t)N_LAYERS * 128 * 4, stream);
    hipMemsetAsync(col + E, 0, 32 * 4, stream);   // pad entries -> node 0 (safe loads)
    int egrid = (E + 255) / 256;
    k_hist<<<egrid, 256, 0, stream>>>(dst, counts, E);
    int b1g = (NN + 1023) / 1024;
    k_scan1<<<b1g, 1024, 0, stream>>>(counts, rowptr, bsum, NN);
    k_scan2<<<1, 1, 0, stream>>>(bsum, b1g);
    k_scan3<<<(NN + 255) / 256, 256, 0, stream>>>(rowptr, cursor, bsum, NN, E);
    int Eh = E / 2;
    k_scatter<<<(Eh + 255) / 256, 256, 0, stream>>>(src, dst, cursor, col, 0, Eh);
    k_scatter<<<(E - Eh + 255) / 256, 256, 0, stream>>>(src, dst, cursor, col, Eh, E);

    // --- input projection ---
    k0<<<NN / 8, 256, 0, stream>>>(x, w0, b0, hA);

    // --- 16 layers ---
    float* hin = hA;
    float* hout = hB;
    for (int i = 0; i < N_LAYERS; i++) {
        k_agg<<<NB1, 256, 0, stream>>>(hin, rowptr, col, lin1_w, lin1_b, z, zsum, i);
        k_bn2<<<NN / 32, 256, 0, stream>>>(z, zsum, gamma, beta, lin2_w, lin2_b, hout, i);
        float* t = hin; hin = hout; hout = t;
    }

    // --- output projection ---
    k_final<<<NN / 8, 256, 0, stream>>>(hin, w16, b16, out);
}

// Round 11
// 1863.643 us; speedup vs baseline: 1.4402x; 1.4402x over previous
//
#include <hip/hip_runtime.h>

#define NN 100000
#define IN_CH 128
#define HID 32
#define OUT_CH 64
#define N_LAYERS 16
#define NB1 2048            // k_agg blocks (4 waves each)
#define EPS_MSG 1e-7f
#define EPS_SM 1e-16f
#define EPS_BN 1e-5f

// ---------------- CSR build (known-good deterministic-order version) ----------------

__global__ void k_hist(const int* __restrict__ dst, int* __restrict__ counts, int E) {
    int i = blockIdx.x * 256 + threadIdx.x;
    if (i < E) atomicAdd(&counts[dst[i]], 1);
}

__global__ void k_scan1(const int* __restrict__ counts, int* __restrict__ rowptr,
                        int* __restrict__ bsum, int n) {
    __shared__ int sh[1024];
    int t = threadIdx.x;
    int i = blockIdx.x * 1024 + t;
    int v = (i < n) ? counts[i] : 0;
    sh[t] = v;
    __syncthreads();
    for (int off = 1; off < 1024; off <<= 1) {
        int tmp = (t >= off) ? sh[t - off] : 0;
        __syncthreads();
        sh[t] += tmp;
        __syncthreads();
    }
    if (i < n) rowptr[i] = sh[t] - v;   // exclusive within chunk
    if (t == 1023) bsum[blockIdx.x] = sh[1023];
}

__global__ void k_scan2(int* __restrict__ bsum, int nb) {
    if (threadIdx.x == 0 && blockIdx.x == 0) {
        int acc = 0;
        for (int b = 0; b < nb; b++) { int v = bsum[b]; bsum[b] = acc; acc += v; }
    }
}

__global__ void k_scan3(int* __restrict__ rowptr, int* __restrict__ cursor,
                        const int* __restrict__ bsum, int n, int E) {
    int i = blockIdx.x * 256 + threadIdx.x;
    if (i < n) {
        int r = rowptr[i] + bsum[i >> 10];
        rowptr[i] = r;
        cursor[i] = r;
    }
    if (i == 0) rowptr[n] = E;
}

// split into [lo,hi) ranges so each dispatch is ~64 us -> layer kernels stay
// visible in the top-5 profile (diagnostic; same atomic mechanism as monolithic)
__global__ void k_scatter(const int* __restrict__ src, const int* __restrict__ dst,
                          int* __restrict__ cursor, int* __restrict__ col,
                          int lo, int hi) {
    int i = lo + blockIdx.x * 256 + threadIdx.x;
    if (i < hi) {
        int d = dst[i];
        int p = atomicAdd(&cursor[d], 1);
        col[p] = src[i];
    }
}

// ---------------- input projection: h0 = x @ w0 + b0 ----------------

__global__ __launch_bounds__(256) void k0(const float* __restrict__ x,
                                          const float* __restrict__ w0,
                                          const float* __restrict__ b0,
                                          float* __restrict__ h) {
    __shared__ float ws[IN_CH * HID];   // 16 KB
    __shared__ float xs[8][IN_CH];      // 4 KB
    int tid = threadIdx.x, c = tid & 31, g = tid >> 5;
    for (int k = tid; k < IN_CH * HID; k += 256) ws[k] = w0[k];
    int d = blockIdx.x * 8 + g;
    float4 xv = ((const float4*)(x + (size_t)d * IN_CH))[c];
    ((float4*)xs[g])[c] = xv;
    __syncthreads();
    float acc = b0[c];
#pragma unroll 16
    for (int k = 0; k < IN_CH; k++) acc += xs[g][k] * ws[k * HID + c];
    h[(size_t)d * HID + c] = acc;
}

// ---------------- per-layer: softmax-agg + residual + lin1 + BN partials ----------------
// WAVE-PER-NODE layout (round-9 proven bits: 77.6-78.6 us, VGPR 32, no spill).
// 3-way wave-uniform chunk dispatch: full 16-edge chunks unmasked; tails <=8
// use a 4-gather path; tails 9..15 keep the masked 8-gather path. r10's SGPR
// col-prefetch REVERTED: it spilled to scratch (WRITE_SIZE 26->402 MB).

__global__ __launch_bounds__(256) void k_agg(const float* __restrict__ h,
                                             const int* __restrict__ rowptr,
                                             const int* __restrict__ col,
                                             const float* __restrict__ w1,
                                             const float* __restrict__ b1,
                                             float* __restrict__ z,
                                             float* __restrict__ zsum,
                                             int layer) {
    __shared__ float red[256];
    int tid = threadIdx.x;
    int c = tid & 31;                                   // channel within half
    int c64 = tid & 63;                                 // owned z column
    int half = (tid >> 5) & 1;                          // even/odd edge slot
    int wslot = __builtin_amdgcn_readfirstlane(tid >> 6);
    int wid = blockIdx.x * 4 + wslot;                   // wave-uniform

    // register-resident W1 column + bias for this lane's output column
    const float* w1l = w1 + layer * (HID * 64);
    float w1col[HID];
#pragma unroll
    for (int k = 0; k < HID; k++) w1col[k] = w1l[k * 64 + c64];
    float b1v = b1[layer * 64 + c64];

    float sz = 0.f, qz = 0.f;

    const int stride = NB1 * 4;
    int pr0 = 0, pr1 = 0;
    if (wid < NN) { pr0 = rowptr[wid]; pr1 = rowptr[wid + 1]; }  // uniform -> s_load

    for (int d = wid; d < NN; d += stride) {
        int r0 = __builtin_amdgcn_readfirstlane(pr0);
        int r1 = __builtin_amdgcn_readfirstlane(pr1);
        // issue next node's rowptr loads now; latency hides under this node's work
        int nd = d + stride;
        if (nd < NN) { pr0 = rowptr[nd]; pr1 = rowptr[nd + 1]; }
        float den = 0.f, num = 0.f;
        int e0 = r0;
        // ---- full 16-edge chunks: unmasked ----
        for (; e0 + 16 <= r1; e0 += 16) {
            float vv[8];
#pragma unroll
            for (int p = 0; p < 8; p++) {
                int sA = col[e0 + 2 * p];               // uniform -> s_load
                int sB = col[e0 + 2 * p + 1];
                int s = half ? sB : sA;
                vv[p] = fmaxf(h[(unsigned)((s << 5) + c)], 0.f) + EPS_MSG;
            }
#pragma unroll
            for (int p = 0; p < 8; p++) {
                float ev = __expf(vv[p]);               // bounded: no max-subtraction
                den += ev;
                num += ev * vv[p];
            }
        }
        int rem = r1 - e0;                              // uniform, 0..15
        if (rem > 8) {
            // ---- tail 9..15: masked 8-gather path (same as original) ----
            float vv[8];
#pragma unroll
            for (int p = 0; p < 8; p++) {
                int sA = col[e0 + 2 * p];
                int sB = col[e0 + 2 * p + 1];           // pad-safe: col has +32 pad
                int s = half ? sB : sA;
                vv[p] = fmaxf(h[(unsigned)((s << 5) + c)], 0.f) + EPS_MSG;
            }
#pragma unroll
            for (int p = 0; p < 8; p++) {
                float ev = __expf(vv[p]);
                bool ok = (2 * p + half) < rem;
                den += ok ? ev : 0.f;
                num += ok ? ev * vv[p] : 0.f;
            }
        } else if (rem > 0) {
            // ---- tail 1..8: masked 4-gather path (omitted terms were +0.0f) ----
            float vv[4];
#pragma unroll
            for (int p = 0; p < 4; p++) {
                int sA = col[e0 + 2 * p];
                int sB = col[e0 + 2 * p + 1];           // pad-safe
                int s = half ? sB : sA;
                vv[p] = fmaxf(h[(unsigned)((s << 5) + c)], 0.f) + EPS_MSG;
            }
#pragma unroll
            for (int p = 0; p < 4; p++) {
                float ev = __expf(vv[p]);
                bool ok = (2 * p + half) < rem;
                den += ok ? ev : 0.f;
                num += ok ? ev * vv[p] : 0.f;
            }
        }
        // merge even/odd partials across the two halves (commutative -> both
        // halves end with bitwise-identical totals)
        den += __shfl_xor(den, 32);
        num += __shfl_xor(num, 32);
        float out = num / (den + EPS_SM) + h[(unsigned)((d << 5) + c)];
        // lin1: z[c64] = b1 + sum_k out[k] * w1[k][c64]; out[k] broadcast via readlane
        float zv = b1v;
#pragma unroll
        for (int k = 0; k < HID; k++) {
            float ok_ = __int_as_float(
                __builtin_amdgcn_readlane(__float_as_int(out), k));
            zv += ok_ * w1col[k];
        }
        z[(size_t)d * 64 + c64] = zv;
        sz += zv; qz += zv * zv;
    }

    // BN partials: block reduce (4 waves, columns match stride 64), 128 atomics/block
    float* acc = zsum + layer * 128;
    red[tid] = sz;
    __syncthreads();
    if (tid < 64) atomicAdd(&acc[tid], red[tid] + red[tid + 64] + red[tid + 128] + red[tid + 192]);
    __syncthreads();
    red[tid] = qz;
    __syncthreads();
    if (tid < 64) atomicAdd(&acc[64 + tid], red[tid] + red[tid + 64] + red[tid + 128] + red[tid + 192]);
}

// ---------------- BN apply + relu + lin2 + relu ----------------
// 128 nodes/block (782 blocks). vs round-8's 32-node version: w2 staging, the
// 64-entry w2col register fill, and the barrier are amortized 4x. Per-node
// arithmetic is UNCHANGED and node->block regrouping reorders no FP ops ->
// bitwise-identical output. LDS 40KB -> 4 blocks/CU (same residency as before).

__global__ __launch_bounds__(256) void k_bn2(const float* __restrict__ z,
                                             const float* __restrict__ zsum,
                                             const float* __restrict__ gamma,
                                             const float* __restrict__ beta,
                                             const float* __restrict__ w2,
                                             const float* __restrict__ b2,
                                             float* __restrict__ hout,
                                             int layer) {
    __shared__ float w2s[64 * HID];   // 8 KB, [k][c] layout
    __shared__ float zs[128][64];     // 32 KB
    int tid = threadIdx.x, c = tid & 31, g = tid >> 5;
    for (int k = tid; k < 64 * HID; k += 256) w2s[k] = w2[layer * (64 * HID) + k];

    // BN scale/shift for channels c and c+32 (same expressions as before -> same bits)
    float S0 = zsum[layer * 128 + c];
    float Q0 = zsum[layer * 128 + 64 + c];
    float mean0 = S0 * (1.0f / NN);
    float var0 = Q0 * (1.0f / NN) - mean0 * mean0;
    float sc0 = gamma[layer * 64 + c] * rsqrtf(var0 + EPS_BN);
    float sh0 = beta[layer * 64 + c] - mean0 * sc0;
    float S1 = zsum[layer * 128 + 32 + c];
    float Q1 = zsum[layer * 128 + 96 + c];
    float mean1 = S1 * (1.0f / NN);
    float var1 = Q1 * (1.0f / NN) - mean1 * mean1;
    float sc1 = gamma[layer * 64 + 32 + c] * rsqrtf(var1 + EPS_BN);
    float sh1 = beta[layer * 64 + 32 + c] - mean1 * sc1;

    int dbase = blockIdx.x * 128;
#pragma unroll
    for (int j = 0; j < 16; j++) {
        int gg = g + 8 * j;
        int d = dbase + gg;
        if (d < NN) {
            float z0 = z[(size_t)d * 64 + c] * sc0 + sh0;
            float z1 = z[(size_t)d * 64 + 32 + c] * sc1 + sh1;
            zs[gg][c] = fmaxf(z0, 0.f);
            zs[gg][c + 32] = fmaxf(z1, 0.f);
        }
    }
    __syncthreads();

    // w2 column into registers (conflict-free LDS reads, once per 16 nodes)
    float w2col[64];
#pragma unroll
    for (int k = 0; k < 64; k++) w2col[k] = w2s[k * HID + c];
    float b2v = b2[layer * HID + c];

#pragma unroll
    for (int j = 0; j < 16; j++) {
        int gg = g + 8 * j;
        int d = dbase + gg;
        if (d < NN) {
            float acc = b2v;
#pragma unroll
            for (int k = 0; k < 64; k += 4) {
                float4 zq = *(const float4*)&zs[gg][k];   // broadcast read
                acc += zq.x * w2col[k];
                acc += zq.y * w2col[k + 1];
                acc += zq.z * w2col[k + 2];
                acc += zq.w * w2col[k + 3];
            }
            hout[(size_t)d * HID + c] = fmaxf(acc, 0.f);
        }
    }
}

// ---------------- output projection: out = h @ w16 + b16 ----------------

__global__ __launch_bounds__(256) void k_final(const float* __restrict__ h,
                                               const float* __restrict__ w16,
                                               const float* __restrict__ b16,
                                               float* __restrict__ out) {
    __shared__ float ws[HID * OUT_CH];   // 8 KB
    __shared__ float hs[8][HID];
    int tid = threadIdx.x, c = tid & 31, g = tid >> 5;
    for (int k = tid; k < HID * OUT_CH; k += 256) ws[k] = w16[k];
    int d = blockIdx.x * 8 + g;
    hs[g][c] = h[(size_t)d * HID + c];
    __syncthreads();
    float o0 = b16[c], o1 = b16[c + 32];
#pragma unroll
    for (int k = 0; k < HID; k++) {
        float hv = hs[g][k];
        o0 += hv * ws[k * OUT_CH + c];
        o1 += hv * ws[k * OUT_CH + c + 32];
    }
    out[(size_t)d * OUT_CH + c] = o0;
    out[(size_t)d * OUT_CH + 32 + c] = o1;
}

// ---------------- host ----------------

extern "C" void kernel_launch(void* const* d_in, const int* in_sizes, int n_in,
                              void* d_out, int out_size, void* d_ws, size_t ws_size,
                              hipStream_t stream) {
    const float* x      = (const float*)d_in[0];
    const int*   ei     = (const int*)d_in[1];
    const float* w0     = (const float*)d_in[2];
    const float* b0     = (const float*)d_in[3];
    const float* lin1_w = (const float*)d_in[4];
    const float* lin1_b = (const float*)d_in[5];
    const float* gamma  = (const float*)d_in[6];
    const float* beta   = (const float*)d_in[7];
    const float* lin2_w = (const float*)d_in[8];
    const float* lin2_b = (const float*)d_in[9];
    const float* w16    = (const float*)d_in[10];
    const float* b16    = (const float*)d_in[11];
    float* out = (float*)d_out;

    const int E = in_sizes[1] / 2;
    const int* src = ei;
    const int* dst = ei + E;

    // workspace carve-up (all 256B-aligned)
    char* p = (char*)d_ws;
    auto alloc = [&](size_t bytes) {
        char* q = p;
        p += (bytes + 255) & ~(size_t)255;
        return q;
    };
    float* hA       = (float*)alloc((size_t)NN * HID * 4);
    float* hB       = (float*)alloc((size_t)NN * HID * 4);
    float* z        = (float*)alloc((size_t)NN * 64 * 4);
    int*   rowptr   = (int*)alloc((size_t)(NN + 1) * 4);
    int*   cursor   = (int*)alloc((size_t)NN * 4);
    int*   counts   = (int*)alloc((size_t)NN * 4);
    int*   col      = (int*)alloc((size_t)(E + 32) * 4);   // +32 pad for chunked reads
    int*   bsum     = (int*)alloc(1024 * 4);
    float* zsum     = (float*)alloc((size_t)N_LAYERS * 128 * 4);
    (void)ws_size; (void)n_in; (void)out_size;

    // --- zero accumulators + CSR build (once per call; reused by all layers) ---
    hipMemsetAsync(counts, 0, (size_t)NN * 4, stream);
    hipMemsetAsync(zsum, 0, (size_t)N_LAYERS * 128 * 4, stream);
    hipMemsetAsync(col + E, 0, 32 * 4, stream);   // pad entries -> node 0 (safe loads)
    int egrid = (E + 255) / 256;
    k_hist<<<egrid, 256, 0, stream>>>(dst, counts, E);
    int b1g = (NN + 1023) / 1024;
    k_scan1<<<b1g, 1024, 0, stream>>>(counts, rowptr, bsum, NN);
    k_scan2<<<1, 1, 0, stream>>>(bsum, b1g);
    k_scan3<<<(NN + 255) / 256, 256, 0, stream>>>(rowptr, cursor, bsum, NN, E);
    int Eh = E / 2;
    k_scatter<<<(Eh + 255) / 256, 256, 0, stream>>>(src, dst, cursor, col, 0, Eh);
    k_scatter<<<(E - Eh + 255) / 256, 256, 0, stream>>>(src, dst, cursor, col, Eh, E);

    // --- input projection ---
    k0<<<NN / 8, 256, 0, stream>>>(x, w0, b0, hA);

    // --- 16 layers ---
    float* hin = hA;
    float* hout = hB;
    for (int i = 0; i < N_LAYERS; i++) {
        k_agg<<<NB1, 256, 0, stream>>>(hin, rowptr, col, lin1_w, lin1_b, z, zsum, i);
        k_bn2<<<(NN + 127) / 128, 256, 0, stream>>>(z, zsum, gamma, beta, lin2_w, lin2_b, hout, i);
        float* t = hin; hin = hout; hout = t;
    }

    // --- output projection ---
    k_final<<<NN / 8, 256, 0, stream>>>(hin, w16, b16, out);
}

// Round 12
// 1421.312 us; speedup vs baseline: 1.8884x; 1.3112x over previous
//
#include <hip/hip_runtime.h>

#define NN 100000
#define IN_CH 128
#define HID 32
#define OUT_CH 64
#define N_LAYERS 16
#define NB1 1024            // k_agg blocks (8 waves each; 8192 waves total, same as before)
#define EPS_MSG 1e-7f
#define EPS_SM 1e-16f
#define EPS_BN 1e-5f

// ---------------- CSR build (known-good deterministic-order version) ----------------

__global__ void k_hist(const int* __restrict__ dst, int* __restrict__ counts, int E) {
    int i = blockIdx.x * 256 + threadIdx.x;
    if (i < E) atomicAdd(&counts[dst[i]], 1);
}

__global__ void k_scan1(const int* __restrict__ counts, int* __restrict__ rowptr,
                        int* __restrict__ bsum, int n) {
    __shared__ int sh[1024];
    int t = threadIdx.x;
    int i = blockIdx.x * 1024 + t;
    int v = (i < n) ? counts[i] : 0;
    sh[t] = v;
    __syncthreads();
    for (int off = 1; off < 1024; off <<= 1) {
        int tmp = (t >= off) ? sh[t - off] : 0;
        __syncthreads();
        sh[t] += tmp;
        __syncthreads();
    }
    if (i < n) rowptr[i] = sh[t] - v;   // exclusive within chunk
    if (t == 1023) bsum[blockIdx.x] = sh[1023];
}

__global__ void k_scan2(int* __restrict__ bsum, int nb) {
    if (threadIdx.x == 0 && blockIdx.x == 0) {
        int acc = 0;
        for (int b = 0; b < nb; b++) { int v = bsum[b]; bsum[b] = acc; acc += v; }
    }
}

__global__ void k_scan3(int* __restrict__ rowptr, int* __restrict__ cursor,
                        const int* __restrict__ bsum, int n, int E) {
    int i = blockIdx.x * 256 + threadIdx.x;
    if (i < n) {
        int r = rowptr[i] + bsum[i >> 10];
        rowptr[i] = r;
        cursor[i] = r;
    }
    if (i == 0) rowptr[n] = E;
}

// split into [lo,hi) ranges so each dispatch is ~64 us -> layer kernels stay
// visible in the top-5 profile (diagnostic; same atomic mechanism as monolithic)
__global__ void k_scatter(const int* __restrict__ src, const int* __restrict__ dst,
                          int* __restrict__ cursor, int* __restrict__ col,
                          int lo, int hi) {
    int i = lo + blockIdx.x * 256 + threadIdx.x;
    if (i < hi) {
        int d = dst[i];
        int p = atomicAdd(&cursor[d], 1);
        col[p] = src[i];
    }
}

// ---------------- input projection: h0 = x @ w0 + b0 ----------------

__global__ __launch_bounds__(256) void k0(const float* __restrict__ x,
                                          const float* __restrict__ w0,
                                          const float* __restrict__ b0,
                                          float* __restrict__ h) {
    __shared__ float ws[IN_CH * HID];   // 16 KB
    __shared__ float xs[8][IN_CH];      // 4 KB
    int tid = threadIdx.x, c = tid & 31, g = tid >> 5;
    for (int k = tid; k < IN_CH * HID; k += 256) ws[k] = w0[k];
    int d = blockIdx.x * 8 + g;
    float4 xv = ((const float4*)(x + (size_t)d * IN_CH))[c];
    ((float4*)xs[g])[c] = xv;
    __syncthreads();
    float acc = b0[c];
#pragma unroll 16
    for (int k = 0; k < IN_CH; k++) acc += xs[g][k] * ws[k * HID + c];
    h[(size_t)d * HID + c] = acc;
}

// ---------------- per-layer: softmax-agg + residual + lin1 + BN partials ----------------
// WAVE-PER-NODE layout (round-9 proven math). OCCUPANCY PROBE: 512-thread
// blocks (8 waves) x 1024 blocks. wid = blockIdx*8 + wslot and stride stays
// 8192, so each wave's node set (and all per-wave arithmetic) is IDENTICAL to
// the 256-thread version. Only the BN block-reduce groups 8 waves instead of 4
// (commutative regroup). Theory: the pinned ~50% occupancy is a co-resident
// WORKGROUP limit (~4/CU); 4 blocks x 8 waves = 32 waves/CU if correct.

__global__ __launch_bounds__(512) void k_agg(const float* __restrict__ h,
                                             const int* __restrict__ rowptr,
                                             const int* __restrict__ col,
                                             const float* __restrict__ w1,
                                             const float* __restrict__ b1,
                                             float* __restrict__ z,
                                             float* __restrict__ zsum,
                                             int layer) {
    __shared__ float red[512];
    int tid = threadIdx.x;
    int c = tid & 31;                                   // channel within half
    int c64 = tid & 63;                                 // owned z column
    int half = (tid >> 5) & 1;                          // even/odd edge slot
    int wslot = __builtin_amdgcn_readfirstlane(tid >> 6);
    int wid = blockIdx.x * 8 + wslot;                   // wave-uniform

    // register-resident W1 column + bias for this lane's output column
    const float* w1l = w1 + layer * (HID * 64);
    float w1col[HID];
#pragma unroll
    for (int k = 0; k < HID; k++) w1col[k] = w1l[k * 64 + c64];
    float b1v = b1[layer * 64 + c64];

    float sz = 0.f, qz = 0.f;

    const int stride = NB1 * 8;                         // 8192 waves, as before
    int pr0 = 0, pr1 = 0;
    if (wid < NN) { pr0 = rowptr[wid]; pr1 = rowptr[wid + 1]; }  // uniform -> s_load

    for (int d = wid; d < NN; d += stride) {
        int r0 = __builtin_amdgcn_readfirstlane(pr0);
        int r1 = __builtin_amdgcn_readfirstlane(pr1);
        // issue next node's rowptr loads now; latency hides under this node's work
        int nd = d + stride;
        if (nd < NN) { pr0 = rowptr[nd]; pr1 = rowptr[nd + 1]; }
        float den = 0.f, num = 0.f;
        int e0 = r0;
        // ---- full 16-edge chunks: unmasked ----
        for (; e0 + 16 <= r1; e0 += 16) {
            float vv[8];
#pragma unroll
            for (int p = 0; p < 8; p++) {
                int sA = col[e0 + 2 * p];               // uniform -> s_load
                int sB = col[e0 + 2 * p + 1];
                int s = half ? sB : sA;
                vv[p] = fmaxf(h[(unsigned)((s << 5) + c)], 0.f) + EPS_MSG;
            }
#pragma unroll
            for (int p = 0; p < 8; p++) {
                float ev = __expf(vv[p]);               // bounded: no max-subtraction
                den += ev;
                num += ev * vv[p];
            }
        }
        int rem = r1 - e0;                              // uniform, 0..15
        if (rem > 8) {
            // ---- tail 9..15: masked 8-gather path (same as original) ----
            float vv[8];
#pragma unroll
            for (int p = 0; p < 8; p++) {
                int sA = col[e0 + 2 * p];
                int sB = col[e0 + 2 * p + 1];           // pad-safe: col has +32 pad
                int s = half ? sB : sA;
                vv[p] = fmaxf(h[(unsigned)((s << 5) + c)], 0.f) + EPS_MSG;
            }
#pragma unroll
            for (int p = 0; p < 8; p++) {
                float ev = __expf(vv[p]);
                bool ok = (2 * p + half) < rem;
                den += ok ? ev : 0.f;
                num += ok ? ev * vv[p] : 0.f;
            }
        } else if (rem > 0) {
            // ---- tail 1..8: masked 4-gather path (omitted terms were +0.0f) ----
            float vv[4];
#pragma unroll
            for (int p = 0; p < 4; p++) {
                int sA = col[e0 + 2 * p];
                int sB = col[e0 + 2 * p + 1];           // pad-safe
                int s = half ? sB : sA;
                vv[p] = fmaxf(h[(unsigned)((s << 5) + c)], 0.f) + EPS_MSG;
            }
#pragma unroll
            for (int p = 0; p < 4; p++) {
                float ev = __expf(vv[p]);
                bool ok = (2 * p + half) < rem;
                den += ok ? ev : 0.f;
                num += ok ? ev * vv[p] : 0.f;
            }
        }
        // merge even/odd partials across the two halves (commutative -> both
        // halves end with bitwise-identical totals)
        den += __shfl_xor(den, 32);
        num += __shfl_xor(num, 32);
        float out = num / (den + EPS_SM) + h[(unsigned)((d << 5) + c)];
        // lin1: z[c64] = b1 + sum_k out[k] * w1[k][c64]; out[k] broadcast via readlane
        float zv = b1v;
#pragma unroll
        for (int k = 0; k < HID; k++) {
            float ok_ = __int_as_float(
                __builtin_amdgcn_readlane(__float_as_int(out), k));
            zv += ok_ * w1col[k];
        }
        z[(size_t)d * 64 + c64] = zv;
        sz += zv; qz += zv * zv;
    }

    // BN partials: block reduce (8 waves, channel stride 64), 128 atomics/block
    float* acc = zsum + layer * 128;
    red[tid] = sz;
    __syncthreads();
    if (tid < 64) {
        float v = 0.f;
#pragma unroll
        for (int w = 0; w < 8; w++) v += red[w * 64 + tid];
        atomicAdd(&acc[tid], v);
    }
    __syncthreads();
    red[tid] = qz;
    __syncthreads();
    if (tid < 64) {
        float v = 0.f;
#pragma unroll
        for (int w = 0; w < 8; w++) v += red[w * 64 + tid];
        atomicAdd(&acc[64 + tid], v);
    }
}

// ---------------- BN apply + relu + lin2 + relu (round-8 proven version) ----------------
// 32 nodes/block (3125 blocks). w2 staged once per block, then each thread
// holds its w2 column in 64 VGPRs (amortized over 4 nodes); zs read as float4
// BROADCASTS (16 LDS ops/node vs 128 in the old version). r11's 128-node
// variant REVERTED: 40KB LDS cut residency, +60us total.

__global__ __launch_bounds__(256) void k_bn2(const float* __restrict__ z,
                                             const float* __restrict__ zsum,
                                             const float* __restrict__ gamma,
                                             const float* __restrict__ beta,
                                             const float* __restrict__ w2,
                                             const float* __restrict__ b2,
                                             float* __restrict__ hout,
                                             int layer) {
    __shared__ float w2s[64 * HID];   // 8 KB, [k][c] layout
    __shared__ float zs[32][64];      // 8 KB
    int tid = threadIdx.x, c = tid & 31, g = tid >> 5;
    for (int k = tid; k < 64 * HID; k += 256) w2s[k] = w2[layer * (64 * HID) + k];

    // BN scale/shift for channels c and c+32 (same expressions as before -> same bits)
    float S0 = zsum[layer * 128 + c];
    float Q0 = zsum[layer * 128 + 64 + c];
    float mean0 = S0 * (1.0f / NN);
    float var0 = Q0 * (1.0f / NN) - mean0 * mean0;
    float sc0 = gamma[layer * 64 + c] * rsqrtf(var0 + EPS_BN);
    float sh0 = beta[layer * 64 + c] - mean0 * sc0;
    float S1 = zsum[layer * 128 + 32 + c];
    float Q1 = zsum[layer * 128 + 96 + c];
    float mean1 = S1 * (1.0f / NN);
    float var1 = Q1 * (1.0f / NN) - mean1 * mean1;
    float sc1 = gamma[layer * 64 + 32 + c] * rsqrtf(var1 + EPS_BN);
    float sh1 = beta[layer * 64 + 32 + c] - mean1 * sc1;

    int dbase = blockIdx.x * 32;
#pragma unroll
    for (int j = 0; j < 4; j++) {
        int gg = g + 8 * j;
        int d = dbase + gg;
        float z0 = z[(size_t)d * 64 + c] * sc0 + sh0;
        float z1 = z[(size_t)d * 64 + 32 + c] * sc1 + sh1;
        zs[gg][c] = fmaxf(z0, 0.f);
        zs[gg][c + 32] = fmaxf(z1, 0.f);
    }
    __syncthreads();

    // w2 column into registers (conflict-free LDS reads, once per 4 nodes)
    float w2col[64];
#pragma unroll
    for (int k = 0; k < 64; k++) w2col[k] = w2s[k * HID + c];
    float b2v = b2[layer * HID + c];

#pragma unroll
    for (int j = 0; j < 4; j++) {
        int gg = g + 8 * j;
        int d = dbase + gg;
        float acc = b2v;
#pragma unroll
        for (int k = 0; k < 64; k += 4) {
            float4 zq = *(const float4*)&zs[gg][k];   // broadcast read
            acc += zq.x * w2col[k];
            acc += zq.y * w2col[k + 1];
            acc += zq.z * w2col[k + 2];
            acc += zq.w * w2col[k + 3];
        }
        hout[(size_t)d * HID + c] = fmaxf(acc, 0.f);
    }
}

// ---------------- output projection: out = h @ w16 + b16 ----------------

__global__ __launch_bounds__(256) void k_final(const float* __restrict__ h,
                                               const float* __restrict__ w16,
                                               const float* __restrict__ b16,
                                               float* __restrict__ out) {
    __shared__ float ws[HID * OUT_CH];   // 8 KB
    __shared__ float hs[8][HID];
    int tid = threadIdx.x, c = tid & 31, g = tid >> 5;
    for (int k = tid; k < HID * OUT_CH; k += 256) ws[k] = w16[k];
    int d = blockIdx.x * 8 + g;
    hs[g][c] = h[(size_t)d * HID + c];
    __syncthreads();
    float o0 = b16[c], o1 = b16[c + 32];
#pragma unroll
    for (int k = 0; k < HID; k++) {
        float hv = hs[g][k];
        o0 += hv * ws[k * OUT_CH + c];
        o1 += hv * ws[k * OUT_CH + c + 32];
    }
    out[(size_t)d * OUT_CH + c] = o0;
    out[(size_t)d * OUT_CH + 32 + c] = o1;
}

// ---------------- host ----------------

extern "C" void kernel_launch(void* const* d_in, const int* in_sizes, int n_in,
                              void* d_out, int out_size, void* d_ws, size_t ws_size,
                              hipStream_t stream) {
    const float* x      = (const float*)d_in[0];
    const int*   ei     = (const int*)d_in[1];
    const float* w0     = (const float*)d_in[2];
    const float* b0     = (const float*)d_in[3];
    const float* lin1_w = (const float*)d_in[4];
    const float* lin1_b = (const float*)d_in[5];
    const float* gamma  = (const float*)d_in[6];
    const float* beta   = (const float*)d_in[7];
    const float* lin2_w = (const float*)d_in[8];
    const float* lin2_b = (const float*)d_in[9];
    const float* w16    = (const float*)d_in[10];
    const float* b16    = (const float*)d_in[11];
    float* out = (float*)d_out;

    const int E = in_sizes[1] / 2;
    const int* src = ei;
    const int* dst = ei + E;

    // workspace carve-up (all 256B-aligned)
    char* p = (char*)d_ws;
    auto alloc = [&](size_t bytes) {
        char* q = p;
        p += (bytes + 255) & ~(size_t)255;
        return q;
    };
    float* hA       = (float*)alloc((size_t)NN * HID * 4);
    float* hB       = (float*)alloc((size_t)NN * HID * 4);
    float* z        = (float*)alloc((size_t)NN * 64 * 4);
    int*   rowptr   = (int*)alloc((size_t)(NN + 1) * 4);
    int*   cursor   = (int*)alloc((size_t)NN * 4);
    int*   counts   = (int*)alloc((size_t)NN * 4);
    int*   col      = (int*)alloc((size_t)(E + 32) * 4);   // +32 pad for chunked reads
    int*   bsum     = (int*)alloc(1024 * 4);
    float* zsum     = (float*)alloc((size_t)N_LAYERS * 128 * 4);
    (void)ws_size; (void)n_in; (void)out_size;

    // --- zero accumulators + CSR build (once per call; reused by all layers) ---
    hipMemsetAsync(counts, 0, (size_t)NN * 4, stream);
    hipMemsetAsync(zsum, 0, (size_t)N_LAYERS * 128 * 4, stream);
    hipMemsetAsync(col + E, 0, 32 * 4, stream);   // pad entries -> node 0 (safe loads)
    int egrid = (E + 255) / 256;
    k_hist<<<egrid, 256, 0, stream>>>(dst, counts, E);
    int b1g = (NN + 1023) / 1024;
    k_scan1<<<b1g, 1024, 0, stream>>>(counts, rowptr, bsum, NN);
    k_scan2<<<1, 1, 0, stream>>>(bsum, b1g);
    k_scan3<<<(NN + 255) / 256, 256, 0, stream>>>(rowptr, cursor, bsum, NN, E);
    int Eh = E / 2;
    k_scatter<<<(Eh + 255) / 256, 256, 0, stream>>>(src, dst, cursor, col, 0, Eh);
    k_scatter<<<(E - Eh + 255) / 256, 256, 0, stream>>>(src, dst, cursor, col, Eh, E);

    // --- input projection ---
    k0<<<NN / 8, 256, 0, stream>>>(x, w0, b0, hA);

    // --- 16 layers ---
    float* hin = hA;
    float* hout = hB;
    for (int i = 0; i < N_LAYERS; i++) {
        k_agg<<<NB1, 512, 0, stream>>>(hin, rowptr, col, lin1_w, lin1_b, z, zsum, i);
        k_bn2<<<NN / 32, 256, 0, stream>>>(z, zsum, gamma, beta, lin2_w, lin2_b, hout, i);
        float* t = hin; hin = hout; hout = t;
    }

    // --- output projection ---
    k_final<<<NN / 8, 256, 0, stream>>>(hin, w16, b16, out);
}